// Round 4
// baseline (9585.455 us; speedup 1.0000x reference)
//
#include <hip/hip_runtime.h>
#include <hip/hip_bf16.h>
#include <float.h>
#include <math.h>

#define NB 256
#define LTXT 77
#define DIM 768
#define DEPTH 12
#define HEADS 12
#define DH 64
#define NTOK 80
#define NKEY 81
#define NROWS (NB*NTOK)       // 20480
#define FFH 3072
#define FF2C 6144
#define INNER 768
#define SROW 100              // f32 per S row (mod-32 = 4 -> 2-way banks)

typedef __hip_bfloat16 bf16;
typedef __attribute__((ext_vector_type(8))) short short8;
typedef __attribute__((ext_vector_type(4))) float f32x4;

__device__ __forceinline__ unsigned short f2bf(float f) {
    __hip_bfloat16 h = __float2bfloat16(f);
    return __builtin_bit_cast(unsigned short, h);
}

// ---------------- token build ----------------
__global__ void build_tokens(const float* __restrict__ text_enc,
                             const float* __restrict__ text_emb,
                             const float* __restrict__ time_tab,
                             const float* __restrict__ lquery,
                             const int* __restrict__ tsteps,
                             float* __restrict__ x) {
    int idx = blockIdx.x * 256 + threadIdx.x;
    if (idx >= NROWS * DIM) return;
    int d = idx % DIM;
    int row = idx / DIM;
    int b = row / NTOK, p = row % NTOK;
    float v;
    if (p < LTXT)            v = text_enc[((size_t)b * LTXT + p) * DIM + d];
    else if (p == LTXT)      v = text_emb[(size_t)b * DIM + d];
    else if (p == LTXT + 1)  v = time_tab[(size_t)tsteps[b] * DIM + d];
    else                     v = lquery[d];
    x[idx] = v;
}

// ---------------- remapped rel-pos bias with mask baked in ----------------
// biasR[h][i][kappa], kappa: 0..79 = token j=kappa+1, 80 = null (j=0), 81..95 = pad
__global__ void build_biasR(const float* __restrict__ table, float* __restrict__ biasR) {
    int idx = blockIdx.x * 256 + threadIdx.x;
    if (idx >= HEADS * NTOK * 96) return;
    int kap = idx % 96;
    int i = (idx / 96) % NTOK;
    int h = idx / (96 * NTOK);
    float v;
    if ((kap < 80 && kap > i) || kap > 80) {
        v = -1e30f;
    } else {
        int j = (kap < 80) ? kap + 1 : 0;
        int rel = j - i;
        int n = rel < 0 ? -rel : 0;
        int bucket;
        if (n < 16) {
            bucket = n;
        } else {
            float val = logf((float)n / 16.0f) / logf(8.0f) * 16.0f;
            int vl = 16 + (int)val;
            bucket = vl < 31 ? vl : 31;
        }
        v = table[bucket * HEADS + h];
    }
    biasR[idx] = v;
}

// ---------------- weight transpose + f32->bf16: W[K][N] -> WT[N][K] ----------------
__global__ __launch_bounds__(256) void convT(const float* __restrict__ W,
                                             bf16* __restrict__ WT,
                                             int K, int N) {
    __shared__ float t[32][33];
    int n0 = blockIdx.x * 32, k0 = blockIdx.y * 32;
    int tx = threadIdx.x & 31, ty = threadIdx.x >> 5;   // 32 x 8
    #pragma unroll
    for (int i = 0; i < 4; i++)
        t[ty + 8 * i][tx] = W[(size_t)(k0 + ty + 8 * i) * N + n0 + tx];
    __syncthreads();
    #pragma unroll
    for (int i = 0; i < 4; i++)
        WT[(size_t)(n0 + ty + 8 * i) * K + k0 + tx] = __float2bfloat16(t[tx][ty + 8 * i]);
}

// ---------------- rmsnorm, wave-per-row, vectorized ----------------
__global__ __launch_bounds__(256) void rmsnorm_w(const float* __restrict__ x,
                                                 const float* __restrict__ gamma,
                                                 bf16* __restrict__ out) {
    int wave = blockIdx.x * 4 + (threadIdx.x >> 6);
    int lane = threadIdx.x & 63;
    float4 g0 = *(const float4*)&gamma[lane * 4];
    float4 g1 = *(const float4*)&gamma[lane * 4 + 256];
    float4 g2 = *(const float4*)&gamma[lane * 4 + 512];
    #pragma unroll 2
    for (int rr = 0; rr < 8; ++rr) {
        int row = wave * 8 + rr;
        const float* xr = x + (size_t)row * DIM + lane * 4;
        float4 v0 = *(const float4*)xr;
        float4 v1 = *(const float4*)(xr + 256);
        float4 v2 = *(const float4*)(xr + 512);
        float ss = v0.x*v0.x + v0.y*v0.y + v0.z*v0.z + v0.w*v0.w
                 + v1.x*v1.x + v1.y*v1.y + v1.z*v1.z + v1.w*v1.w
                 + v2.x*v2.x + v2.y*v2.y + v2.z*v2.z + v2.w*v2.w;
        #pragma unroll
        for (int o = 32; o > 0; o >>= 1) ss += __shfl_xor(ss, o);
        float inv = 27.712812921102035f / sqrtf(ss + 1e-5f);
        bf16* orow = out + (size_t)row * DIM + lane * 4;
        ushort4 w0 = { f2bf(v0.x*inv*g0.x), f2bf(v0.y*inv*g0.y), f2bf(v0.z*inv*g0.z), f2bf(v0.w*inv*g0.w) };
        ushort4 w1 = { f2bf(v1.x*inv*g1.x), f2bf(v1.y*inv*g1.y), f2bf(v1.z*inv*g1.z), f2bf(v1.w*inv*g1.w) };
        ushort4 w2 = { f2bf(v2.x*inv*g2.x), f2bf(v2.y*inv*g2.y), f2bf(v2.z*inv*g2.z), f2bf(v2.w*inv*g2.w) };
        *(ushort4*)(orow)       = w0;
        *(ushort4*)(orow + 256) = w1;
        *(ushort4*)(orow + 512) = w2;
    }
}

// =========================================================================
// bf16 MFMA GEMM via global_load_lds (m97 structure): C[M,N] (+)= A @ BT^T
// 128x128 tile, BK=64, 256 thr = 4 waves (2x2), 4x4 frags of 16x16x32.
// LDS dest linear (HW requirement); conflict-free via pre-swizzled global
// source chunk (c ^ row&7) + same XOR on fragment read (involution).
// =========================================================================

#define GSTAGE(lds, base, b0, ld)                                              \
    _Pragma("unroll")                                                          \
    for (int r_ = 0; r_ < 4; ++r_) {                                           \
        int idx_ = r_ * 256 + t;                                               \
        int row_ = idx_ >> 3, c_ = idx_ & 7;                                   \
        int cs_ = c_ ^ (row_ & 7);                                             \
        __builtin_amdgcn_global_load_lds(                                      \
            (const __attribute__((address_space(1))) unsigned int*)            \
                &base[(size_t)(b0 + row_) * ld + k0 + cs_ * 8],                \
            (__attribute__((address_space(3))) unsigned int*)&lds[idx_ * 8],   \
            16, 0, 0);                                                         \
    }

#define FRAG_READ(dst, lds, base_row, kk)                                      \
    _Pragma("unroll")                                                          \
    for (int q_ = 0; q_ < 4; ++q_) {                                           \
        int row_ = (base_row) + q_ * 16 + fr;                                  \
        int ch_ = ((((kk) << 2) + kb) ^ (row_ & 7));                           \
        dst[q_] = *(const short8*)&lds[row_ * 64 + ch_ * 8];                   \
    }

// EPI: 1 = C(f32) += acc ; 2 = C(bf16) = acc
template<int EPI>
__global__ __launch_bounds__(256) void gemm_bt(const bf16* __restrict__ A,
                                               const bf16* __restrict__ BT,
                                               float* __restrict__ C,
                                               int N, int K) {
    __shared__ __align__(16) short As[128 * 64];
    __shared__ __align__(16) short Bs[128 * 64];
    const int t = threadIdx.x;
    const int lane = t & 63;
    const int wid = t >> 6;
    const int wr = wid >> 1, wc = wid & 1;
    const int fr = lane & 15;
    const int kb = lane >> 4;
    const int row0 = blockIdx.y * 128, col0 = blockIdx.x * 128;

    f32x4 acc[4][4] = {};
    const int NKT = K >> 6;

    for (int kt = 0; kt < NKT; ++kt) {
        int k0 = kt << 6;
        GSTAGE(As, A, row0, K)
        GSTAGE(Bs, BT, col0, K)
        __syncthreads();
        #pragma unroll
        for (int kk = 0; kk < 2; ++kk) {
            short8 af[4], bv[4];
            FRAG_READ(af, As, wr * 64, kk)
            FRAG_READ(bv, Bs, wc * 64, kk)
            #pragma unroll
            for (int i = 0; i < 4; ++i)
                #pragma unroll
                for (int j = 0; j < 4; ++j)
                    acc[i][j] = __builtin_amdgcn_mfma_f32_16x16x32_bf16(af[i], bv[j], acc[i][j], 0, 0, 0);
        }
        __syncthreads();
    }

    #pragma unroll
    for (int i = 0; i < 4; ++i) {
        #pragma unroll
        for (int j = 0; j < 4; ++j) {
            int row = row0 + wr * 64 + i * 16 + kb * 4;
            int col = col0 + wc * 64 + j * 16 + fr;
            #pragma unroll
            for (int r = 0; r < 4; ++r) {
                size_t o = (size_t)(row + r) * N + col;
                if (EPI == 1)      C[o] += acc[i][j][r];
                else               ((bf16*)C)[o] = __float2bfloat16(acc[i][j][r]);
            }
        }
    }
}

// KV projection: N=128. cols 0..63 -> kout[row][64] bf16; cols 64..127 -> vT[b][d][tok] bf16
__global__ __launch_bounds__(256) void gemm_kv(const bf16* __restrict__ A,
                                               const bf16* __restrict__ BT,
                                               bf16* __restrict__ kout,
                                               bf16* __restrict__ vT) {
    __shared__ __align__(16) short As[128 * 64];
    __shared__ __align__(16) short Bs[128 * 64];
    const int t = threadIdx.x;
    const int lane = t & 63;
    const int wid = t >> 6;
    const int wr = wid >> 1, wc = wid & 1;
    const int fr = lane & 15;
    const int kb = lane >> 4;
    const int row0 = blockIdx.y * 128;
    const int K = DIM;

    f32x4 acc[4][4] = {};

    for (int kt = 0; kt < (DIM >> 6); ++kt) {
        int k0 = kt << 6;
        GSTAGE(As, A, row0, K)
        GSTAGE(Bs, BT, 0, K)
        __syncthreads();
        #pragma unroll
        for (int kk = 0; kk < 2; ++kk) {
            short8 af[4], bv[4];
            FRAG_READ(af, As, wr * 64, kk)
            FRAG_READ(bv, Bs, wc * 64, kk)
            #pragma unroll
            for (int i = 0; i < 4; ++i)
                #pragma unroll
                for (int j = 0; j < 4; ++j)
                    acc[i][j] = __builtin_amdgcn_mfma_f32_16x16x32_bf16(af[i], bv[j], acc[i][j], 0, 0, 0);
        }
        __syncthreads();
    }

    #pragma unroll
    for (int i = 0; i < 4; ++i) {
        #pragma unroll
        for (int j = 0; j < 4; ++j) {
            int row = row0 + wr * 64 + i * 16 + kb * 4;
            int col = wc * 64 + j * 16 + fr;
            #pragma unroll
            for (int r = 0; r < 4; ++r) {
                int rg = row + r;
                float v = acc[i][j][r];
                if (wc == 0) {
                    kout[(size_t)rg * 64 + col] = __float2bfloat16(v);
                } else {
                    int bb = rg / NTOK, ii = rg - bb * NTOK;
                    vT[((size_t)bb * 64 + (col - 64)) * NTOK + ii] = __float2bfloat16(v);
                }
            }
        }
    }
}

// =========================================================================
// MFMA attention: one block per (b,h), 4 waves.
// keys kappa: 0..79 tokens, 80 null, 81..95 pad (masked via biasR)
// =========================================================================
__global__ __launch_bounds__(256) void attn_mfma(const bf16* __restrict__ qb,
                                                 const bf16* __restrict__ kbuf,
                                                 const bf16* __restrict__ vT,
                                                 const float* __restrict__ nullkv,  // [2][64] this layer
                                                 const float* __restrict__ biasR,
                                                 bf16* __restrict__ attnb) {
    const int b = blockIdx.x / HEADS;
    const int h = blockIdx.x % HEADS;
    __shared__ __align__(16) short Ks[96 * 64];    // swizzled 16B chunks
    __shared__ __align__(16) short Vt[64 * 128];   // [d][kappa], swizzled
    __shared__ __align__(16) float Sls[80 * SROW]; // P bf16 in-place after softmax
    char* Sb = (char*)Sls;
    const int t = threadIdx.x;
    const int lane = t & 63;
    const int wid = t >> 6;
    const int g = lane >> 4;
    const int fr = lane & 15;

    // ---- stage K: 96 rows x 8 chunks ----
    for (int c = t; c < 768; c += 256) {
        int row = c >> 3, ch = c & 7;
        short8 v;
        if (row < NTOK) {
            v = *(const short8*)&kbuf[((size_t)(b * NTOK + row)) * 64 + ch * 8];
        } else if (row == NTOK) {
            #pragma unroll
            for (int e = 0; e < 8; ++e) v[e] = (short)f2bf(nullkv[ch * 8 + e]);
        } else {
            v = short8{0,0,0,0,0,0,0,0};
        }
        *(short8*)((char*)Ks + row * 128 + ((ch ^ (row & 7)) << 4)) = v;
    }
    // ---- stage Vt: 64 d-rows x 16 chunks (12 used) ----
    for (int c = t; c < 1024; c += 256) {
        int d = c >> 4, ch = c & 15;
        if (ch >= 12) continue;
        short8 v;
        if (ch < 10) {
            v = *(const short8*)&vT[((size_t)b * 64 + d) * NTOK + ch * 8];
        } else if (ch == 10) {
            v = short8{0,0,0,0,0,0,0,0};
            v[0] = (short)f2bf(nullkv[64 + d]);   // kappa = 80 (null V)
        } else {
            v = short8{0,0,0,0,0,0,0,0};
        }
        *(short8*)((char*)Vt + d * 256 + ((ch ^ (d & 7)) << 4)) = v;
    }
    __syncthreads();

    // ---- S = 0.125 * Q K^T + biasR ; 30 tiles (5m x 6n) strided over waves ----
    const bf16* qbase = qb + ((size_t)(b * NTOK)) * INNER + h * DH;
    for (int s = 0; s < 8; ++s) {
        int tt = wid + 4 * s;
        if (tt >= 30) break;
        int m = tt / 6, n = tt - 6 * m;
        f32x4 acc = {};
        #pragma unroll
        for (int kk = 0; kk < 2; ++kk) {
            short8 a = *(const short8*)&qbase[(size_t)(m * 16 + fr) * INNER + kk * 32 + g * 8];
            int krow = n * 16 + fr;
            short8 kf = *(const short8*)((const char*)Ks + krow * 128 + ((((kk << 2) + g) ^ (krow & 7)) << 4));
            acc = __builtin_amdgcn_mfma_f32_16x16x32_bf16(a, kf, acc, 0, 0, 0);
        }
        int i0 = m * 16 + g * 4;
        int kap = n * 16 + fr;
        const float* bR = biasR + ((size_t)h * NTOK + i0) * 96 + kap;
        #pragma unroll
        for (int r = 0; r < 4; ++r)
            Sls[(i0 + r) * SROW + kap] = acc[r] * 0.125f + bR[r * 96];
    }
    __syncthreads();

    // ---- softmax per row (20 rows per wave), write P bf16 in place ----
    for (int rr = 0; rr < 20; ++rr) {
        int row = wid + 4 * rr;
        const float* Srow = Sls + row * SROW;
        float s0 = Srow[lane];
        float s1v = Srow[64 + (lane & 31)];
        float mx = fmaxf(s0, s1v);
        #pragma unroll
        for (int o = 32; o > 0; o >>= 1) mx = fmaxf(mx, __shfl_xor(mx, o));
        float e0 = __expf(s0 - mx);
        float e1 = (lane < 32) ? __expf(s1v - mx) : 0.0f;
        float sum = e0 + e1;
        #pragma unroll
        for (int o = 32; o > 0; o >>= 1) sum += __shfl_xor(sum, o);
        float inv = 1.0f / sum;
        *(unsigned short*)(Sb + row * (SROW * 4) + lane * 2) = f2bf(e0 * inv);
        if (lane < 32)
            *(unsigned short*)(Sb + row * (SROW * 4) + 128 + lane * 2) = f2bf(e1 * inv);
    }
    __syncthreads();

    // ---- O = P V ; 20 tiles (5m x 4n), 5 per wave ----
    for (int s = 0; s < 5; ++s) {
        int tt = wid + 4 * s;
        int m = tt >> 2, n = tt & 3;
        f32x4 acc = {};
        #pragma unroll
        for (int kc = 0; kc < 3; ++kc) {
            short8 p = *(const short8*)(Sb + (m * 16 + fr) * (SROW * 4) + kc * 64 + g * 16);
            int drow = n * 16 + fr;
            short8 vv = *(const short8*)((const char*)Vt + drow * 256 + ((((kc << 2) + g) ^ (drow & 7)) << 4));
            acc = __builtin_amdgcn_mfma_f32_16x16x32_bf16(p, vv, acc, 0, 0, 0);
        }
        int i0 = m * 16 + g * 4;
        int d = n * 16 + fr;
        #pragma unroll
        for (int r = 0; r < 4; ++r)
            attnb[((size_t)(b * NTOK) + i0 + r) * INNER + h * DH + d] = __float2bfloat16(acc[r]);
    }
}

// fused FF1: act[M,3072] = (xn @ W1a) * silu(xn @ W1g), bf16 out
__global__ __launch_bounds__(256) void gemm_ff1(const bf16* __restrict__ A,
                                                const bf16* __restrict__ W1T,
                                                bf16* __restrict__ act) {
    __shared__ __align__(16) short As[128 * 64];
    __shared__ __align__(16) short Bs1[128 * 64];
    __shared__ __align__(16) short Bs2[128 * 64];
    const int t = threadIdx.x;
    const int lane = t & 63;
    const int wid = t >> 6;
    const int wr = wid >> 1, wc = wid & 1;
    const int fr = lane & 15;
    const int kb = lane >> 4;
    const int row0 = blockIdx.y * 128, col0 = blockIdx.x * 128;
    const int K = DIM;
    const bf16* B1 = W1T;
    const bf16* B2 = W1T + (size_t)FFH * DIM;

    f32x4 acc1[4][4] = {}, acc2[4][4] = {};

    for (int kt = 0; kt < (DIM >> 6); ++kt) {
        int k0 = kt << 6;
        GSTAGE(As, A, row0, K)
        GSTAGE(Bs1, B1, col0, K)
        GSTAGE(Bs2, B2, col0, K)
        __syncthreads();
        #pragma unroll
        for (int kk = 0; kk < 2; ++kk) {
            short8 af[4], b1v[4], b2v[4];
            FRAG_READ(af, As, wr * 64, kk)
            FRAG_READ(b1v, Bs1, wc * 64, kk)
            FRAG_READ(b2v, Bs2, wc * 64, kk)
            #pragma unroll
            for (int i = 0; i < 4; ++i)
                #pragma unroll
                for (int j = 0; j < 4; ++j) {
                    acc1[i][j] = __builtin_amdgcn_mfma_f32_16x16x32_bf16(af[i], b1v[j], acc1[i][j], 0, 0, 0);
                    acc2[i][j] = __builtin_amdgcn_mfma_f32_16x16x32_bf16(af[i], b2v[j], acc2[i][j], 0, 0, 0);
                }
        }
        __syncthreads();
    }

    #pragma unroll
    for (int i = 0; i < 4; ++i) {
        #pragma unroll
        for (int j = 0; j < 4; ++j) {
            int row = row0 + wr * 64 + i * 16 + kb * 4;
            int col = col0 + wc * 64 + j * 16 + fr;
            #pragma unroll
            for (int r = 0; r < 4; ++r) {
                float a = acc1[i][j][r];
                float gt = acc2[i][j][r];
                float s = a * gt / (1.0f + __expf(-gt));
                act[(size_t)(row + r) * FFH + col] = __float2bfloat16(s);
            }
        }
    }
}

// ---------------- output extraction ----------------
__global__ void extract(const float* __restrict__ x, float* __restrict__ out) {
    int idx = blockIdx.x * 256 + threadIdx.x;
    if (idx >= NB * DIM) return;
    int b = idx / DIM, d = idx % DIM;
    out[idx] = x[((size_t)(b * NTOK + NTOK - 1)) * DIM + d];
}

extern "C" void kernel_launch(void* const* d_in, const int* in_sizes, int n_in,
                              void* d_out, int out_size, void* d_ws, size_t ws_size,
                              hipStream_t stream) {
    (void)in_sizes; (void)n_in; (void)out_size; (void)ws_size;
    const float* text_enc = (const float*)d_in[1];
    const float* text_emb = (const float*)d_in[2];
    const float* time_tab = (const float*)d_in[3];
    const float* lquery   = (const float*)d_in[4];
    const float* rel_tab  = (const float*)d_in[5];
    const float* attn_g   = (const float*)d_in[6];
    const float* Wq       = (const float*)d_in[7];
    const float* Wkv      = (const float*)d_in[8];
    const float* Wout     = (const float*)d_in[9];
    const float* null_kv  = (const float*)d_in[10];
    const float* ff_g     = (const float*)d_in[11];
    const float* Wff1     = (const float*)d_in[12];
    const float* Wff2     = (const float*)d_in[13];
    const int*   tsteps   = (const int*)d_in[14];

    // ---- workspace layout (bytes, all 16-aligned) ----
    char* ws = (char*)d_ws;
    float* x     = (float*)(ws);                        // 62,914,560
    bf16*  xn    = (bf16*)(ws + 62914560);              // 31,457,280 (attn out aliases)
    bf16*  attnb = xn;
    char*  U     = ws + 94371840;                       // union region: 125,829,120
    bf16*  qb    = (bf16*)U;                            //  31,457,280
    bf16*  kbuf  = (bf16*)(U + 31457280);               //   2,621,440
    bf16*  vT    = (bf16*)(U + 34078720);               //   2,621,440
    bf16*  act   = (bf16*)U;                            // 125,829,120 (FF phase)
    float* biasR = (float*)(ws + 220200960);            //     368,640
    bf16*  WqT   = (bf16*)(ws + 220569600);             //   1,179,648
    bf16*  WkvT  = (bf16*)(ws + 221749248);             //     196,608
    bf16*  WoutT = (bf16*)(ws + 221945856);             //   1,179,648
    bf16*  Wff1T = (bf16*)(ws + 223125504);             //   9,437,184
    bf16*  Wff2T = (bf16*)(ws + 232562688);             //   4,718,592  -> end 237,281,280

    build_tokens<<<(NROWS * DIM + 255) / 256, 256, 0, stream>>>(text_enc, text_emb, time_tab, lquery, tsteps, x);
    build_biasR<<<(HEADS * NTOK * 96 + 255) / 256, 256, 0, stream>>>(rel_tab, biasR);

    for (int l = 0; l < DEPTH; l++) {
        convT<<<dim3(INNER / 32, DIM / 32), 256, 0, stream>>>(Wq   + (size_t)l * DIM * INNER,  WqT,   DIM,   INNER);
        convT<<<dim3((2 * DH) / 32, DIM / 32), 256, 0, stream>>>(Wkv + (size_t)l * DIM * 2 * DH, WkvT, DIM, 2 * DH);
        convT<<<dim3(DIM / 32, INNER / 32), 256, 0, stream>>>(Wout + (size_t)l * INNER * DIM,  WoutT, INNER, DIM);
        convT<<<dim3(FF2C / 32, DIM / 32), 256, 0, stream>>>(Wff1 + (size_t)l * DIM * FF2C,    Wff1T, DIM,   FF2C);
        convT<<<dim3(DIM / 32, FFH / 32), 256, 0, stream>>>(Wff2  + (size_t)l * FFH * DIM,     Wff2T, FFH,   DIM);

        // ---- attention block ----
        rmsnorm_w<<<NROWS / (8 * 4), 256, 0, stream>>>(x, attn_g + (size_t)l * DIM, xn);
        gemm_bt<2><<<dim3(INNER / 128, NROWS / 128), 256, 0, stream>>>(xn, WqT, (float*)qb, INNER, DIM);
        gemm_kv<<<dim3(1, NROWS / 128), 256, 0, stream>>>(xn, WkvT, kbuf, vT);
        attn_mfma<<<NB * HEADS, 256, 0, stream>>>(qb, kbuf, vT, null_kv + (size_t)l * 2 * DH, biasR, attnb);
        gemm_bt<1><<<dim3(DIM / 128, NROWS / 128), 256, 0, stream>>>(attnb, WoutT, x, DIM, INNER);

        // ---- feedforward block ----
        rmsnorm_w<<<NROWS / (8 * 4), 256, 0, stream>>>(x, ff_g + (size_t)l * DIM, xn);
        gemm_ff1<<<dim3(FFH / 128, NROWS / 128), 256, 0, stream>>>(xn, Wff1T, act);
        gemm_bt<1><<<dim3(DIM / 128, NROWS / 128), 256, 0, stream>>>(act, Wff2T, x, DIM, FFH);
    }

    extract<<<(NB * DIM + 255) / 256, 256, 0, stream>>>(x, (float*)d_out);
}

// Round 5
// 9570.670 us; speedup vs baseline: 1.0015x; 1.0015x over previous
//
#include <hip/hip_runtime.h>
#include <hip/hip_bf16.h>
#include <float.h>
#include <math.h>

#define NB 256
#define LTXT 77
#define DIM 768
#define DEPTH 12
#define HEADS 12
#define DH 64
#define NTOK 80
#define NKEY 81
#define NROWS (NB*NTOK)       // 20480
#define FFH 3072
#define FF2C 6144
#define INNER 768
#define SROW 100              // f32 per S row (mod-32 = 4 -> 2-way banks)

typedef __hip_bfloat16 bf16;
typedef __attribute__((ext_vector_type(8))) short short8;
typedef __attribute__((ext_vector_type(4))) float f32x4;

#define BARRIER() asm volatile("s_barrier" ::: "memory")
#define WAITV(n)  asm volatile("s_waitcnt vmcnt(" #n ")" ::: "memory")

__device__ __forceinline__ unsigned short f2bf(float f) {
    __hip_bfloat16 h = __float2bfloat16(f);
    return __builtin_bit_cast(unsigned short, h);
}

// XCD-chunked block swizzle (requires nwg % 8 == 0 — true for all GEMM grids here)
__device__ __forceinline__ void xcd_swz(int& bx, int& by) {
    int gx = gridDim.x;
    int nwg = gx * gridDim.y;
    int lid = blockIdx.y * gx + blockIdx.x;
    int w = (lid & 7) * (nwg >> 3) + (lid >> 3);
    bx = w % gx;
    by = w / gx;
}

// ---------------- token build ----------------
__global__ void build_tokens(const float* __restrict__ text_enc,
                             const float* __restrict__ text_emb,
                             const float* __restrict__ time_tab,
                             const float* __restrict__ lquery,
                             const int* __restrict__ tsteps,
                             float* __restrict__ x) {
    int idx = blockIdx.x * 256 + threadIdx.x;
    if (idx >= NROWS * DIM) return;
    int d = idx % DIM;
    int row = idx / DIM;
    int b = row / NTOK, p = row % NTOK;
    float v;
    if (p < LTXT)            v = text_enc[((size_t)b * LTXT + p) * DIM + d];
    else if (p == LTXT)      v = text_emb[(size_t)b * DIM + d];
    else if (p == LTXT + 1)  v = time_tab[(size_t)tsteps[b] * DIM + d];
    else                     v = lquery[d];
    x[idx] = v;
}

// ---------------- remapped rel-pos bias with mask baked in ----------------
// biasR[h][i][kappa], kappa: 0..79 = token j=kappa+1, 80 = null (j=0), 81..95 = pad
__global__ void build_biasR(const float* __restrict__ table, float* __restrict__ biasR) {
    int idx = blockIdx.x * 256 + threadIdx.x;
    if (idx >= HEADS * NTOK * 96) return;
    int kap = idx % 96;
    int i = (idx / 96) % NTOK;
    int h = idx / (96 * NTOK);
    float v;
    if ((kap < 80 && kap > i) || kap > 80) {
        v = -1e30f;
    } else {
        int j = (kap < 80) ? kap + 1 : 0;
        int rel = j - i;
        int n = rel < 0 ? -rel : 0;
        int bucket;
        if (n < 16) {
            bucket = n;
        } else {
            float val = logf((float)n / 16.0f) / logf(8.0f) * 16.0f;
            int vl = 16 + (int)val;
            bucket = vl < 31 ? vl : 31;
        }
        v = table[bucket * HEADS + h];
    }
    biasR[idx] = v;
}

// ---------------- weight transpose + f32->bf16: W[K][N] -> WT[N][K] ----------------
__global__ __launch_bounds__(256) void convT(const float* __restrict__ W,
                                             bf16* __restrict__ WT,
                                             int K, int N) {
    __shared__ float t[32][33];
    int n0 = blockIdx.x * 32, k0 = blockIdx.y * 32;
    int tx = threadIdx.x & 31, ty = threadIdx.x >> 5;   // 32 x 8
    #pragma unroll
    for (int i = 0; i < 4; i++)
        t[ty + 8 * i][tx] = W[(size_t)(k0 + ty + 8 * i) * N + n0 + tx];
    __syncthreads();
    #pragma unroll
    for (int i = 0; i < 4; i++)
        WT[(size_t)(n0 + ty + 8 * i) * K + k0 + tx] = __float2bfloat16(t[tx][ty + 8 * i]);
}

// ---------------- rmsnorm, wave-per-row, vectorized ----------------
__global__ __launch_bounds__(256) void rmsnorm_w(const float* __restrict__ x,
                                                 const float* __restrict__ gamma,
                                                 bf16* __restrict__ out) {
    int wave = blockIdx.x * 4 + (threadIdx.x >> 6);
    int lane = threadIdx.x & 63;
    float4 g0 = *(const float4*)&gamma[lane * 4];
    float4 g1 = *(const float4*)&gamma[lane * 4 + 256];
    float4 g2 = *(const float4*)&gamma[lane * 4 + 512];
    #pragma unroll 2
    for (int rr = 0; rr < 8; ++rr) {
        int row = wave * 8 + rr;
        const float* xr = x + (size_t)row * DIM + lane * 4;
        float4 v0 = *(const float4*)xr;
        float4 v1 = *(const float4*)(xr + 256);
        float4 v2 = *(const float4*)(xr + 512);
        float ss = v0.x*v0.x + v0.y*v0.y + v0.z*v0.z + v0.w*v0.w
                 + v1.x*v1.x + v1.y*v1.y + v1.z*v1.z + v1.w*v1.w
                 + v2.x*v2.x + v2.y*v2.y + v2.z*v2.z + v2.w*v2.w;
        #pragma unroll
        for (int o = 32; o > 0; o >>= 1) ss += __shfl_xor(ss, o);
        float inv = 27.712812921102035f / sqrtf(ss + 1e-5f);
        bf16* orow = out + (size_t)row * DIM + lane * 4;
        ushort4 w0 = { f2bf(v0.x*inv*g0.x), f2bf(v0.y*inv*g0.y), f2bf(v0.z*inv*g0.z), f2bf(v0.w*inv*g0.w) };
        ushort4 w1 = { f2bf(v1.x*inv*g1.x), f2bf(v1.y*inv*g1.y), f2bf(v1.z*inv*g1.z), f2bf(v1.w*inv*g1.w) };
        ushort4 w2 = { f2bf(v2.x*inv*g2.x), f2bf(v2.y*inv*g2.y), f2bf(v2.z*inv*g2.z), f2bf(v2.w*inv*g2.w) };
        *(ushort4*)(orow)       = w0;
        *(ushort4*)(orow + 256) = w1;
        *(ushort4*)(orow + 512) = w2;
    }
}

// =========================================================================
// bf16 MFMA GEMM via global_load_lds, DOUBLE-BUFFERED with counted vmcnt
// (T3-min + T4): issue next tile's loads, wait only for current tile
// (vmcnt(N) with N = next-tile load count), raw s_barrier (no full drain).
// 128x128 tile, BK=64, 256 thr = 4 waves (2x2), 4x4 frags of 16x16x32.
// LDS dest linear (HW req); conflict-free via pre-swizzled global source
// chunk (c ^ row&7) + same XOR on fragment read (involution).
// =========================================================================

#define GSTAGE(lds, base, b0, ld, kk0)                                         \
    _Pragma("unroll")                                                          \
    for (int r_ = 0; r_ < 4; ++r_) {                                           \
        int idx_ = r_ * 256 + t;                                               \
        int row_ = idx_ >> 3, c_ = idx_ & 7;                                   \
        int cs_ = c_ ^ (row_ & 7);                                             \
        __builtin_amdgcn_global_load_lds(                                      \
            (const __attribute__((address_space(1))) unsigned int*)            \
                &base[(size_t)(b0 + row_) * ld + (kk0) + cs_ * 8],             \
            (__attribute__((address_space(3))) unsigned int*)&lds[idx_ * 8],   \
            16, 0, 0);                                                         \
    }

#define FRAG_READ(dst, lds, base_row, kk)                                      \
    _Pragma("unroll")                                                          \
    for (int q_ = 0; q_ < 4; ++q_) {                                           \
        int row_ = (base_row) + q_ * 16 + fr;                                  \
        int ch_ = ((((kk) << 2) + kb) ^ (row_ & 7));                           \
        dst[q_] = *(const short8*)&lds[row_ * 64 + ch_ * 8];                   \
    }

// EPI: 1 = C(f32) += acc ; 2 = C(bf16) = acc
template<int EPI>
__global__ __launch_bounds__(256) void gemm_bt(const bf16* __restrict__ A,
                                               const bf16* __restrict__ BT,
                                               float* __restrict__ C,
                                               int N, int K) {
    __shared__ __align__(16) short As[2 * 128 * 64];
    __shared__ __align__(16) short Bs[2 * 128 * 64];
    const int t = threadIdx.x;
    const int lane = t & 63;
    const int wid = t >> 6;
    const int wr = wid >> 1, wc = wid & 1;
    const int fr = lane & 15;
    const int kb = lane >> 4;
    int bx, by;
    xcd_swz(bx, by);
    const int row0 = by * 128, col0 = bx * 128;

    f32x4 acc[4][4] = {};
    const int NKT = K >> 6;

    GSTAGE(As, A, row0, K, 0)
    GSTAGE(Bs, BT, col0, K, 0)

    for (int kt = 0; kt < NKT; ++kt) {
        const short* curA = As + (kt & 1) * (128 * 64);
        const short* curB = Bs + (kt & 1) * (128 * 64);
        if (kt + 1 < NKT) {
            short* nxtA = As + ((kt + 1) & 1) * (128 * 64);
            short* nxtB = Bs + ((kt + 1) & 1) * (128 * 64);
            int k0n = (kt + 1) << 6;
            GSTAGE(nxtA, A, row0, K, k0n)
            GSTAGE(nxtB, BT, col0, K, k0n)
            WAITV(8);       // current tile's 8 loads done; next 8 stay in flight
        } else {
            WAITV(0);
        }
        BARRIER();
        #pragma unroll
        for (int kk = 0; kk < 2; ++kk) {
            short8 af[4], bv[4];
            FRAG_READ(af, curA, wr * 64, kk)
            FRAG_READ(bv, curB, wc * 64, kk)
            __builtin_amdgcn_s_setprio(1);
            #pragma unroll
            for (int i = 0; i < 4; ++i)
                #pragma unroll
                for (int j = 0; j < 4; ++j)
                    acc[i][j] = __builtin_amdgcn_mfma_f32_16x16x32_bf16(af[i], bv[j], acc[i][j], 0, 0, 0);
            __builtin_amdgcn_s_setprio(0);
        }
        BARRIER();
    }

    #pragma unroll
    for (int i = 0; i < 4; ++i) {
        #pragma unroll
        for (int j = 0; j < 4; ++j) {
            int row = row0 + wr * 64 + i * 16 + kb * 4;
            int col = col0 + wc * 64 + j * 16 + fr;
            #pragma unroll
            for (int r = 0; r < 4; ++r) {
                size_t o = (size_t)(row + r) * N + col;
                if (EPI == 1)      C[o] += acc[i][j][r];
                else               ((bf16*)C)[o] = __float2bfloat16(acc[i][j][r]);
            }
        }
    }
}

// KV projection: N=128. cols 0..63 -> kout[row][64] bf16; cols 64..127 -> vT[b][d][tok] bf16
__global__ __launch_bounds__(256) void gemm_kv(const bf16* __restrict__ A,
                                               const bf16* __restrict__ BT,
                                               bf16* __restrict__ kout,
                                               bf16* __restrict__ vT) {
    __shared__ __align__(16) short As[2 * 128 * 64];
    __shared__ __align__(16) short Bs[2 * 128 * 64];
    const int t = threadIdx.x;
    const int lane = t & 63;
    const int wid = t >> 6;
    const int wr = wid >> 1, wc = wid & 1;
    const int fr = lane & 15;
    const int kb = lane >> 4;
    int bx, by;
    xcd_swz(bx, by);
    const int row0 = by * 128;
    const int K = DIM;

    f32x4 acc[4][4] = {};
    const int NKT = DIM >> 6;

    GSTAGE(As, A, row0, K, 0)
    GSTAGE(Bs, BT, 0, K, 0)

    for (int kt = 0; kt < NKT; ++kt) {
        const short* curA = As + (kt & 1) * (128 * 64);
        const short* curB = Bs + (kt & 1) * (128 * 64);
        if (kt + 1 < NKT) {
            short* nxtA = As + ((kt + 1) & 1) * (128 * 64);
            short* nxtB = Bs + ((kt + 1) & 1) * (128 * 64);
            int k0n = (kt + 1) << 6;
            GSTAGE(nxtA, A, row0, K, k0n)
            GSTAGE(nxtB, BT, 0, K, k0n)
            WAITV(8);
        } else {
            WAITV(0);
        }
        BARRIER();
        #pragma unroll
        for (int kk = 0; kk < 2; ++kk) {
            short8 af[4], bv[4];
            FRAG_READ(af, curA, wr * 64, kk)
            FRAG_READ(bv, curB, wc * 64, kk)
            __builtin_amdgcn_s_setprio(1);
            #pragma unroll
            for (int i = 0; i < 4; ++i)
                #pragma unroll
                for (int j = 0; j < 4; ++j)
                    acc[i][j] = __builtin_amdgcn_mfma_f32_16x16x32_bf16(af[i], bv[j], acc[i][j], 0, 0, 0);
            __builtin_amdgcn_s_setprio(0);
        }
        BARRIER();
    }

    #pragma unroll
    for (int i = 0; i < 4; ++i) {
        #pragma unroll
        for (int j = 0; j < 4; ++j) {
            int row = row0 + wr * 64 + i * 16 + kb * 4;
            int col = wc * 64 + j * 16 + fr;
            #pragma unroll
            for (int r = 0; r < 4; ++r) {
                int rg = row + r;
                float v = acc[i][j][r];
                if (wc == 0) {
                    kout[(size_t)rg * 64 + col] = __float2bfloat16(v);
                } else {
                    int bb = rg / NTOK, ii = rg - bb * NTOK;
                    vT[((size_t)bb * 64 + (col - 64)) * NTOK + ii] = __float2bfloat16(v);
                }
            }
        }
    }
}

// =========================================================================
// MFMA attention: one block per (b,h), 4 waves. (unchanged from round 3)
// =========================================================================
__global__ __launch_bounds__(256) void attn_mfma(const bf16* __restrict__ qb,
                                                 const bf16* __restrict__ kbuf,
                                                 const bf16* __restrict__ vT,
                                                 const float* __restrict__ nullkv,  // [2][64] this layer
                                                 const float* __restrict__ biasR,
                                                 bf16* __restrict__ attnb) {
    const int b = blockIdx.x / HEADS;
    const int h = blockIdx.x % HEADS;
    __shared__ __align__(16) short Ks[96 * 64];
    __shared__ __align__(16) short Vt[64 * 128];
    __shared__ __align__(16) float Sls[80 * SROW];
    char* Sb = (char*)Sls;
    const int t = threadIdx.x;
    const int lane = t & 63;
    const int wid = t >> 6;
    const int g = lane >> 4;
    const int fr = lane & 15;

    for (int c = t; c < 768; c += 256) {
        int row = c >> 3, ch = c & 7;
        short8 v;
        if (row < NTOK) {
            v = *(const short8*)&kbuf[((size_t)(b * NTOK + row)) * 64 + ch * 8];
        } else if (row == NTOK) {
            #pragma unroll
            for (int e = 0; e < 8; ++e) v[e] = (short)f2bf(nullkv[ch * 8 + e]);
        } else {
            v = short8{0,0,0,0,0,0,0,0};
        }
        *(short8*)((char*)Ks + row * 128 + ((ch ^ (row & 7)) << 4)) = v;
    }
    for (int c = t; c < 1024; c += 256) {
        int d = c >> 4, ch = c & 15;
        if (ch >= 12) continue;
        short8 v;
        if (ch < 10) {
            v = *(const short8*)&vT[((size_t)b * 64 + d) * NTOK + ch * 8];
        } else if (ch == 10) {
            v = short8{0,0,0,0,0,0,0,0};
            v[0] = (short)f2bf(nullkv[64 + d]);
        } else {
            v = short8{0,0,0,0,0,0,0,0};
        }
        *(short8*)((char*)Vt + d * 256 + ((ch ^ (d & 7)) << 4)) = v;
    }
    __syncthreads();

    const bf16* qbase = qb + ((size_t)(b * NTOK)) * INNER + h * DH;
    for (int s = 0; s < 8; ++s) {
        int tt = wid + 4 * s;
        if (tt >= 30) break;
        int m = tt / 6, n = tt - 6 * m;
        f32x4 acc = {};
        #pragma unroll
        for (int kk = 0; kk < 2; ++kk) {
            short8 a = *(const short8*)&qbase[(size_t)(m * 16 + fr) * INNER + kk * 32 + g * 8];
            int krow = n * 16 + fr;
            short8 kf = *(const short8*)((const char*)Ks + krow * 128 + ((((kk << 2) + g) ^ (krow & 7)) << 4));
            acc = __builtin_amdgcn_mfma_f32_16x16x32_bf16(a, kf, acc, 0, 0, 0);
        }
        int i0 = m * 16 + g * 4;
        int kap = n * 16 + fr;
        const float* bR = biasR + ((size_t)h * NTOK + i0) * 96 + kap;
        #pragma unroll
        for (int r = 0; r < 4; ++r)
            Sls[(i0 + r) * SROW + kap] = acc[r] * 0.125f + bR[r * 96];
    }
    __syncthreads();

    for (int rr = 0; rr < 20; ++rr) {
        int row = wid + 4 * rr;
        const float* Srow = Sls + row * SROW;
        float s0 = Srow[lane];
        float s1v = Srow[64 + (lane & 31)];
        float mx = fmaxf(s0, s1v);
        #pragma unroll
        for (int o = 32; o > 0; o >>= 1) mx = fmaxf(mx, __shfl_xor(mx, o));
        float e0 = __expf(s0 - mx);
        float e1 = (lane < 32) ? __expf(s1v - mx) : 0.0f;
        float sum = e0 + e1;
        #pragma unroll
        for (int o = 32; o > 0; o >>= 1) sum += __shfl_xor(sum, o);
        float inv = 1.0f / sum;
        *(unsigned short*)(Sb + row * (SROW * 4) + lane * 2) = f2bf(e0 * inv);
        if (lane < 32)
            *(unsigned short*)(Sb + row * (SROW * 4) + 128 + lane * 2) = f2bf(e1 * inv);
    }
    __syncthreads();

    for (int s = 0; s < 5; ++s) {
        int tt = wid + 4 * s;
        int m = tt >> 2, n = tt & 3;
        f32x4 acc = {};
        #pragma unroll
        for (int kc = 0; kc < 3; ++kc) {
            short8 p = *(const short8*)(Sb + (m * 16 + fr) * (SROW * 4) + kc * 64 + g * 16);
            int drow = n * 16 + fr;
            short8 vv = *(const short8*)((const char*)Vt + drow * 256 + ((((kc << 2) + g) ^ (drow & 7)) << 4));
            acc = __builtin_amdgcn_mfma_f32_16x16x32_bf16(p, vv, acc, 0, 0, 0);
        }
        int i0 = m * 16 + g * 4;
        int d = n * 16 + fr;
        #pragma unroll
        for (int r = 0; r < 4; ++r)
            attnb[((size_t)(b * NTOK) + i0 + r) * INNER + h * DH + d] = __float2bfloat16(acc[r]);
    }
}

// fused FF1: act[M,3072] = (xn @ W1a) * silu(xn @ W1g), bf16 out. dbuf + counted vmcnt.
__global__ __launch_bounds__(256) void gemm_ff1(const bf16* __restrict__ A,
                                                const bf16* __restrict__ W1T,
                                                bf16* __restrict__ act) {
    __shared__ __align__(16) short As[2 * 128 * 64];
    __shared__ __align__(16) short Bs1[2 * 128 * 64];
    __shared__ __align__(16) short Bs2[2 * 128 * 64];
    const int t = threadIdx.x;
    const int lane = t & 63;
    const int wid = t >> 6;
    const int wr = wid >> 1, wc = wid & 1;
    const int fr = lane & 15;
    const int kb = lane >> 4;
    int bx, by;
    xcd_swz(bx, by);
    const int row0 = by * 128, col0 = bx * 128;
    const int K = DIM;
    const bf16* B1 = W1T;
    const bf16* B2 = W1T + (size_t)FFH * DIM;

    f32x4 acc1[4][4] = {}, acc2[4][4] = {};
    const int NKT = DIM >> 6;

    GSTAGE(As, A, row0, K, 0)
    GSTAGE(Bs1, B1, col0, K, 0)
    GSTAGE(Bs2, B2, col0, K, 0)

    for (int kt = 0; kt < NKT; ++kt) {
        const short* curA  = As  + (kt & 1) * (128 * 64);
        const short* curB1 = Bs1 + (kt & 1) * (128 * 64);
        const short* curB2 = Bs2 + (kt & 1) * (128 * 64);
        if (kt + 1 < NKT) {
            short* nxtA  = As  + ((kt + 1) & 1) * (128 * 64);
            short* nxtB1 = Bs1 + ((kt + 1) & 1) * (128 * 64);
            short* nxtB2 = Bs2 + ((kt + 1) & 1) * (128 * 64);
            int k0n = (kt + 1) << 6;
            GSTAGE(nxtA, A, row0, K, k0n)
            GSTAGE(nxtB1, B1, col0, K, k0n)
            GSTAGE(nxtB2, B2, col0, K, k0n)
            WAITV(12);      // current tile's 12 loads done; next 12 in flight
        } else {
            WAITV(0);
        }
        BARRIER();
        #pragma unroll
        for (int kk = 0; kk < 2; ++kk) {
            short8 af[4], b1v[4], b2v[4];
            FRAG_READ(af, curA, wr * 64, kk)
            FRAG_READ(b1v, curB1, wc * 64, kk)
            FRAG_READ(b2v, curB2, wc * 64, kk)
            __builtin_amdgcn_s_setprio(1);
            #pragma unroll
            for (int i = 0; i < 4; ++i)
                #pragma unroll
                for (int j = 0; j < 4; ++j) {
                    acc1[i][j] = __builtin_amdgcn_mfma_f32_16x16x32_bf16(af[i], b1v[j], acc1[i][j], 0, 0, 0);
                    acc2[i][j] = __builtin_amdgcn_mfma_f32_16x16x32_bf16(af[i], b2v[j], acc2[i][j], 0, 0, 0);
                }
            __builtin_amdgcn_s_setprio(0);
        }
        BARRIER();
    }

    #pragma unroll
    for (int i = 0; i < 4; ++i) {
        #pragma unroll
        for (int j = 0; j < 4; ++j) {
            int row = row0 + wr * 64 + i * 16 + kb * 4;
            int col = col0 + wc * 64 + j * 16 + fr;
            #pragma unroll
            for (int r = 0; r < 4; ++r) {
                float a = acc1[i][j][r];
                float gt = acc2[i][j][r];
                float s = a * gt / (1.0f + __expf(-gt));
                act[(size_t)(row + r) * FFH + col] = __float2bfloat16(s);
            }
        }
    }
}

// ---------------- output extraction ----------------
__global__ void extract(const float* __restrict__ x, float* __restrict__ out) {
    int idx = blockIdx.x * 256 + threadIdx.x;
    if (idx >= NB * DIM) return;
    int b = idx / DIM, d = idx % DIM;
    out[idx] = x[((size_t)(b * NTOK + NTOK - 1)) * DIM + d];
}

extern "C" void kernel_launch(void* const* d_in, const int* in_sizes, int n_in,
                              void* d_out, int out_size, void* d_ws, size_t ws_size,
                              hipStream_t stream) {
    (void)in_sizes; (void)n_in; (void)out_size; (void)ws_size;
    const float* text_enc = (const float*)d_in[1];
    const float* text_emb = (const float*)d_in[2];
    const float* time_tab = (const float*)d_in[3];
    const float* lquery   = (const float*)d_in[4];
    const float* rel_tab  = (const float*)d_in[5];
    const float* attn_g   = (const float*)d_in[6];
    const float* Wq       = (const float*)d_in[7];
    const float* Wkv      = (const float*)d_in[8];
    const float* Wout     = (const float*)d_in[9];
    const float* null_kv  = (const float*)d_in[10];
    const float* ff_g     = (const float*)d_in[11];
    const float* Wff1     = (const float*)d_in[12];
    const float* Wff2     = (const float*)d_in[13];
    const int*   tsteps   = (const int*)d_in[14];

    // ---- workspace layout (bytes, all 16-aligned) ----
    char* ws = (char*)d_ws;
    float* x     = (float*)(ws);                        // 62,914,560
    bf16*  xn    = (bf16*)(ws + 62914560);              // 31,457,280 (attn out aliases)
    bf16*  attnb = xn;
    char*  U     = ws + 94371840;                       // union region: 125,829,120
    bf16*  qb    = (bf16*)U;                            //  31,457,280
    bf16*  kbuf  = (bf16*)(U + 31457280);               //   2,621,440
    bf16*  vT    = (bf16*)(U + 34078720);               //   2,621,440
    bf16*  act   = (bf16*)U;                            // 125,829,120 (FF phase)
    float* biasR = (float*)(ws + 220200960);            //     368,640
    bf16*  WqT   = (bf16*)(ws + 220569600);             //   1,179,648
    bf16*  WkvT  = (bf16*)(ws + 221749248);             //     196,608
    bf16*  WoutT = (bf16*)(ws + 221945856);             //   1,179,648
    bf16*  Wff1T = (bf16*)(ws + 223125504);             //   9,437,184
    bf16*  Wff2T = (bf16*)(ws + 232562688);             //   4,718,592  -> end 237,281,280

    build_tokens<<<(NROWS * DIM + 255) / 256, 256, 0, stream>>>(text_enc, text_emb, time_tab, lquery, tsteps, x);
    build_biasR<<<(HEADS * NTOK * 96 + 255) / 256, 256, 0, stream>>>(rel_tab, biasR);

    for (int l = 0; l < DEPTH; l++) {
        convT<<<dim3(INNER / 32, DIM / 32), 256, 0, stream>>>(Wq   + (size_t)l * DIM * INNER,  WqT,   DIM,   INNER);
        convT<<<dim3((2 * DH) / 32, DIM / 32), 256, 0, stream>>>(Wkv + (size_t)l * DIM * 2 * DH, WkvT, DIM, 2 * DH);
        convT<<<dim3(DIM / 32, INNER / 32), 256, 0, stream>>>(Wout + (size_t)l * INNER * DIM,  WoutT, INNER, DIM);
        convT<<<dim3(FF2C / 32, DIM / 32), 256, 0, stream>>>(Wff1 + (size_t)l * DIM * FF2C,    Wff1T, DIM,   FF2C);
        convT<<<dim3(DIM / 32, FFH / 32), 256, 0, stream>>>(Wff2  + (size_t)l * FFH * DIM,     Wff2T, FFH,   DIM);

        // ---- attention block ----
        rmsnorm_w<<<NROWS / (8 * 4), 256, 0, stream>>>(x, attn_g + (size_t)l * DIM, xn);
        gemm_bt<2><<<dim3(INNER / 128, NROWS / 128), 256, 0, stream>>>(xn, WqT, (float*)qb, INNER, DIM);
        gemm_kv<<<dim3(1, NROWS / 128), 256, 0, stream>>>(xn, WkvT, kbuf, vT);
        attn_mfma<<<NB * HEADS, 256, 0, stream>>>(qb, kbuf, vT, null_kv + (size_t)l * 2 * DH, biasR, attnb);
        gemm_bt<1><<<dim3(DIM / 128, NROWS / 128), 256, 0, stream>>>(attnb, WoutT, x, DIM, INNER);

        // ---- feedforward block ----
        rmsnorm_w<<<NROWS / (8 * 4), 256, 0, stream>>>(x, ff_g + (size_t)l * DIM, xn);
        gemm_ff1<<<dim3(FFH / 128, NROWS / 128), 256, 0, stream>>>(xn, Wff1T, act);
        gemm_bt<1><<<dim3(DIM / 128, NROWS / 128), 256, 0, stream>>>(act, Wff2T, x, DIM, FFH);
    }

    extract<<<(NB * DIM + 255) / 256, 256, 0, stream>>>(x, (float*)d_out);
}

// Round 6
// 7894.379 us; speedup vs baseline: 1.2142x; 1.2123x over previous
//
#include <hip/hip_runtime.h>
#include <hip/hip_bf16.h>
#include <float.h>
#include <math.h>

#define NB 256
#define LTXT 77
#define DIM 768
#define DEPTH 12
#define HEADS 12
#define DH 64
#define NTOK 80
#define NKEY 81
#define NROWS (NB*NTOK)       // 20480
#define FFH 3072
#define FF2C 6144
#define INNER 768
#define SROW 100              // f32 per S row (mod-32 = 4 -> 2-way banks)

typedef __hip_bfloat16 bf16;
typedef __attribute__((ext_vector_type(8))) short short8;
typedef __attribute__((ext_vector_type(4))) float f32x4;

#define BARRIER() asm volatile("s_barrier" ::: "memory")
#define WAITV(n)  asm volatile("s_waitcnt vmcnt(" #n ")" ::: "memory")

__device__ __forceinline__ unsigned short f2bf(float f) {
    __hip_bfloat16 h = __float2bfloat16(f);
    return __builtin_bit_cast(unsigned short, h);
}

// ---------------- token build ----------------
__global__ void build_tokens(const float* __restrict__ text_enc,
                             const float* __restrict__ text_emb,
                             const float* __restrict__ time_tab,
                             const float* __restrict__ lquery,
                             const int* __restrict__ tsteps,
                             float* __restrict__ x) {
    int idx = blockIdx.x * 256 + threadIdx.x;
    if (idx >= NROWS * DIM) return;
    int d = idx % DIM;
    int row = idx / DIM;
    int b = row / NTOK, p = row % NTOK;
    float v;
    if (p < LTXT)            v = text_enc[((size_t)b * LTXT + p) * DIM + d];
    else if (p == LTXT)      v = text_emb[(size_t)b * DIM + d];
    else if (p == LTXT + 1)  v = time_tab[(size_t)tsteps[b] * DIM + d];
    else                     v = lquery[d];
    x[idx] = v;
}

// ---------------- remapped rel-pos bias with mask baked in ----------------
// biasR[h][i][kappa], kappa: 0..79 = token j=kappa+1, 80 = null (j=0), 81..95 = pad
__global__ void build_biasR(const float* __restrict__ table, float* __restrict__ biasR) {
    int idx = blockIdx.x * 256 + threadIdx.x;
    if (idx >= HEADS * NTOK * 96) return;
    int kap = idx % 96;
    int i = (idx / 96) % NTOK;
    int h = idx / (96 * NTOK);
    float v;
    if ((kap < 80 && kap > i) || kap > 80) {
        v = -1e30f;
    } else {
        int j = (kap < 80) ? kap + 1 : 0;
        int rel = j - i;
        int n = rel < 0 ? -rel : 0;
        int bucket;
        if (n < 16) {
            bucket = n;
        } else {
            float val = logf((float)n / 16.0f) / logf(8.0f) * 16.0f;
            int vl = 16 + (int)val;
            bucket = vl < 31 ? vl : 31;
        }
        v = table[bucket * HEADS + h];
    }
    biasR[idx] = v;
}

// ---------------- weight transpose + f32->bf16: W[K][N] -> WT[N][K] ----------------
__global__ __launch_bounds__(256) void convT(const float* __restrict__ W,
                                             bf16* __restrict__ WT,
                                             int K, int N) {
    __shared__ float t[32][33];
    int n0 = blockIdx.x * 32, k0 = blockIdx.y * 32;
    int tx = threadIdx.x & 31, ty = threadIdx.x >> 5;   // 32 x 8
    #pragma unroll
    for (int i = 0; i < 4; i++)
        t[ty + 8 * i][tx] = W[(size_t)(k0 + ty + 8 * i) * N + n0 + tx];
    __syncthreads();
    #pragma unroll
    for (int i = 0; i < 4; i++)
        WT[(size_t)(n0 + ty + 8 * i) * K + k0 + tx] = __float2bfloat16(t[tx][ty + 8 * i]);
}

// ---------------- rmsnorm, wave-per-row, vectorized ----------------
__global__ __launch_bounds__(256) void rmsnorm_w(const float* __restrict__ x,
                                                 const float* __restrict__ gamma,
                                                 bf16* __restrict__ out) {
    int wave = blockIdx.x * 4 + (threadIdx.x >> 6);
    int lane = threadIdx.x & 63;
    float4 g0 = *(const float4*)&gamma[lane * 4];
    float4 g1 = *(const float4*)&gamma[lane * 4 + 256];
    float4 g2 = *(const float4*)&gamma[lane * 4 + 512];
    #pragma unroll 2
    for (int rr = 0; rr < 8; ++rr) {
        int row = wave * 8 + rr;
        const float* xr = x + (size_t)row * DIM + lane * 4;
        float4 v0 = *(const float4*)xr;
        float4 v1 = *(const float4*)(xr + 256);
        float4 v2 = *(const float4*)(xr + 512);
        float ss = v0.x*v0.x + v0.y*v0.y + v0.z*v0.z + v0.w*v0.w
                 + v1.x*v1.x + v1.y*v1.y + v1.z*v1.z + v1.w*v1.w
                 + v2.x*v2.x + v2.y*v2.y + v2.z*v2.z + v2.w*v2.w;
        #pragma unroll
        for (int o = 32; o > 0; o >>= 1) ss += __shfl_xor(ss, o);
        float inv = 27.712812921102035f / sqrtf(ss + 1e-5f);
        bf16* orow = out + (size_t)row * DIM + lane * 4;
        ushort4 w0 = { f2bf(v0.x*inv*g0.x), f2bf(v0.y*inv*g0.y), f2bf(v0.z*inv*g0.z), f2bf(v0.w*inv*g0.w) };
        ushort4 w1 = { f2bf(v1.x*inv*g1.x), f2bf(v1.y*inv*g1.y), f2bf(v1.z*inv*g1.z), f2bf(v1.w*inv*g1.w) };
        ushort4 w2 = { f2bf(v2.x*inv*g2.x), f2bf(v2.y*inv*g2.y), f2bf(v2.z*inv*g2.z), f2bf(v2.w*inv*g2.w) };
        *(ushort4*)(orow)       = w0;
        *(ushort4*)(orow + 256) = w1;
        *(ushort4*)(orow + 512) = w2;
    }
}

// =========================================================================
// bf16 MFMA GEMM via global_load_lds, double-buffered, counted vmcnt,
// raw s_barrier, setprio around MFMA clusters. No XCD swizzle (hurt L2).
// GSTAGE_N: nld 16B-loads per thread; rows = nld*32.
// =========================================================================

#define GSTAGE_N(nld, lds, base, b0, ld, kk0)                                  \
    _Pragma("unroll")                                                          \
    for (int r_ = 0; r_ < (nld); ++r_) {                                       \
        int idx_ = r_ * 256 + t;                                               \
        int row_ = idx_ >> 3, c_ = idx_ & 7;                                   \
        int cs_ = c_ ^ (row_ & 7);                                             \
        __builtin_amdgcn_global_load_lds(                                      \
            (const __attribute__((address_space(1))) unsigned int*)            \
                &base[(size_t)(b0 + row_) * ld + (kk0) + cs_ * 8],             \
            (__attribute__((address_space(3))) unsigned int*)&lds[idx_ * 8],   \
            16, 0, 0);                                                         \
    }

#define FRAG_READ(dst, lds, base_row, kk)                                      \
    _Pragma("unroll")                                                          \
    for (int q_ = 0; q_ < 4; ++q_) {                                           \
        int row_ = (base_row) + q_ * 16 + fr;                                  \
        int ch_ = ((((kk) << 2) + kb) ^ (row_ & 7));                           \
        dst[q_] = *(const short8*)&lds[row_ * 64 + ch_ * 8];                   \
    }

#define FRAG_READ2(dst, lds, base_row, kk)                                     \
    _Pragma("unroll")                                                          \
    for (int q_ = 0; q_ < 2; ++q_) {                                           \
        int row_ = (base_row) + q_ * 16 + fr;                                  \
        int ch_ = ((((kk) << 2) + kb) ^ (row_ & 7));                           \
        dst[q_] = *(const short8*)&lds[row_ * 64 + ch_ * 8];                   \
    }

// EPI: 1 = C(f32) += acc ; 2 = C(bf16) = acc
template<int EPI>
__global__ __launch_bounds__(256, 2) void gemm_bt(const bf16* __restrict__ A,
                                                  const bf16* __restrict__ BT,
                                                  float* __restrict__ C,
                                                  int N, int K) {
    __shared__ __align__(16) short As[2 * 128 * 64];
    __shared__ __align__(16) short Bs[2 * 128 * 64];
    const int t = threadIdx.x;
    const int lane = t & 63;
    const int wid = t >> 6;
    const int wr = wid >> 1, wc = wid & 1;
    const int fr = lane & 15;
    const int kb = lane >> 4;
    const int row0 = blockIdx.y * 128, col0 = blockIdx.x * 128;

    f32x4 acc[4][4] = {};
    const int NKT = K >> 6;

    GSTAGE_N(4, As, A, row0, K, 0)
    GSTAGE_N(4, Bs, BT, col0, K, 0)

    for (int kt = 0; kt < NKT; ++kt) {
        const short* curA = As + (kt & 1) * (128 * 64);
        const short* curB = Bs + (kt & 1) * (128 * 64);
        if (kt + 1 < NKT) {
            short* nxtA = As + ((kt + 1) & 1) * (128 * 64);
            short* nxtB = Bs + ((kt + 1) & 1) * (128 * 64);
            int k0n = (kt + 1) << 6;
            GSTAGE_N(4, nxtA, A, row0, K, k0n)
            GSTAGE_N(4, nxtB, BT, col0, K, k0n)
            WAITV(8);       // current tile's 8 loads done; next 8 stay in flight
        } else {
            WAITV(0);
        }
        BARRIER();
        #pragma unroll
        for (int kk = 0; kk < 2; ++kk) {
            short8 af[4], bv[4];
            FRAG_READ(af, curA, wr * 64, kk)
            FRAG_READ(bv, curB, wc * 64, kk)
            __builtin_amdgcn_s_setprio(1);
            #pragma unroll
            for (int i = 0; i < 4; ++i)
                #pragma unroll
                for (int j = 0; j < 4; ++j)
                    acc[i][j] = __builtin_amdgcn_mfma_f32_16x16x32_bf16(af[i], bv[j], acc[i][j], 0, 0, 0);
            __builtin_amdgcn_s_setprio(0);
        }
        BARRIER();
    }

    #pragma unroll
    for (int i = 0; i < 4; ++i) {
        #pragma unroll
        for (int j = 0; j < 4; ++j) {
            int row = row0 + wr * 64 + i * 16 + kb * 4;
            int col = col0 + wc * 64 + j * 16 + fr;
            #pragma unroll
            for (int r = 0; r < 4; ++r) {
                size_t o = (size_t)(row + r) * N + col;
                if (EPI == 1)      C[o] += acc[i][j][r];
                else               ((bf16*)C)[o] = __float2bfloat16(acc[i][j][r]);
            }
        }
    }
}

// KV projection: N=128. cols 0..63 -> kout[row][64] bf16; cols 64..127 -> vT[b][d][tok] bf16
__global__ __launch_bounds__(256, 2) void gemm_kv(const bf16* __restrict__ A,
                                                  const bf16* __restrict__ BT,
                                                  bf16* __restrict__ kout,
                                                  bf16* __restrict__ vT) {
    __shared__ __align__(16) short As[2 * 128 * 64];
    __shared__ __align__(16) short Bs[2 * 128 * 64];
    const int t = threadIdx.x;
    const int lane = t & 63;
    const int wid = t >> 6;
    const int wr = wid >> 1, wc = wid & 1;
    const int fr = lane & 15;
    const int kb = lane >> 4;
    const int row0 = blockIdx.y * 128;
    const int K = DIM;

    f32x4 acc[4][4] = {};
    const int NKT = DIM >> 6;

    GSTAGE_N(4, As, A, row0, K, 0)
    GSTAGE_N(4, Bs, BT, 0, K, 0)

    for (int kt = 0; kt < NKT; ++kt) {
        const short* curA = As + (kt & 1) * (128 * 64);
        const short* curB = Bs + (kt & 1) * (128 * 64);
        if (kt + 1 < NKT) {
            short* nxtA = As + ((kt + 1) & 1) * (128 * 64);
            short* nxtB = Bs + ((kt + 1) & 1) * (128 * 64);
            int k0n = (kt + 1) << 6;
            GSTAGE_N(4, nxtA, A, row0, K, k0n)
            GSTAGE_N(4, nxtB, BT, 0, K, k0n)
            WAITV(8);
        } else {
            WAITV(0);
        }
        BARRIER();
        #pragma unroll
        for (int kk = 0; kk < 2; ++kk) {
            short8 af[4], bv[4];
            FRAG_READ(af, curA, wr * 64, kk)
            FRAG_READ(bv, curB, wc * 64, kk)
            __builtin_amdgcn_s_setprio(1);
            #pragma unroll
            for (int i = 0; i < 4; ++i)
                #pragma unroll
                for (int j = 0; j < 4; ++j)
                    acc[i][j] = __builtin_amdgcn_mfma_f32_16x16x32_bf16(af[i], bv[j], acc[i][j], 0, 0, 0);
            __builtin_amdgcn_s_setprio(0);
        }
        BARRIER();
    }

    #pragma unroll
    for (int i = 0; i < 4; ++i) {
        #pragma unroll
        for (int j = 0; j < 4; ++j) {
            int row = row0 + wr * 64 + i * 16 + kb * 4;
            int col = wc * 64 + j * 16 + fr;
            #pragma unroll
            for (int r = 0; r < 4; ++r) {
                int rg = row + r;
                float v = acc[i][j][r];
                if (wc == 0) {
                    kout[(size_t)rg * 64 + col] = __float2bfloat16(v);
                } else {
                    int bb = rg / NTOK, ii = rg - bb * NTOK;
                    vT[((size_t)bb * 64 + (col - 64)) * NTOK + ii] = __float2bfloat16(v);
                }
            }
        }
    }
}

// =========================================================================
// MFMA attention: one block per (b,h), 4 waves. (unchanged)
// =========================================================================
__global__ __launch_bounds__(256) void attn_mfma(const bf16* __restrict__ qb,
                                                 const bf16* __restrict__ kbuf,
                                                 const bf16* __restrict__ vT,
                                                 const float* __restrict__ nullkv,  // [2][64] this layer
                                                 const float* __restrict__ biasR,
                                                 bf16* __restrict__ attnb) {
    const int b = blockIdx.x / HEADS;
    const int h = blockIdx.x % HEADS;
    __shared__ __align__(16) short Ks[96 * 64];
    __shared__ __align__(16) short Vt[64 * 128];
    __shared__ __align__(16) float Sls[80 * SROW];
    char* Sb = (char*)Sls;
    const int t = threadIdx.x;
    const int lane = t & 63;
    const int wid = t >> 6;
    const int g = lane >> 4;
    const int fr = lane & 15;

    for (int c = t; c < 768; c += 256) {
        int row = c >> 3, ch = c & 7;
        short8 v;
        if (row < NTOK) {
            v = *(const short8*)&kbuf[((size_t)(b * NTOK + row)) * 64 + ch * 8];
        } else if (row == NTOK) {
            #pragma unroll
            for (int e = 0; e < 8; ++e) v[e] = (short)f2bf(nullkv[ch * 8 + e]);
        } else {
            v = short8{0,0,0,0,0,0,0,0};
        }
        *(short8*)((char*)Ks + row * 128 + ((ch ^ (row & 7)) << 4)) = v;
    }
    for (int c = t; c < 1024; c += 256) {
        int d = c >> 4, ch = c & 15;
        if (ch >= 12) continue;
        short8 v;
        if (ch < 10) {
            v = *(const short8*)&vT[((size_t)b * 64 + d) * NTOK + ch * 8];
        } else if (ch == 10) {
            v = short8{0,0,0,0,0,0,0,0};
            v[0] = (short)f2bf(nullkv[64 + d]);
        } else {
            v = short8{0,0,0,0,0,0,0,0};
        }
        *(short8*)((char*)Vt + d * 256 + ((ch ^ (d & 7)) << 4)) = v;
    }
    __syncthreads();

    const bf16* qbase = qb + ((size_t)(b * NTOK)) * INNER + h * DH;
    for (int s = 0; s < 8; ++s) {
        int tt = wid + 4 * s;
        if (tt >= 30) break;
        int m = tt / 6, n = tt - 6 * m;
        f32x4 acc = {};
        #pragma unroll
        for (int kk = 0; kk < 2; ++kk) {
            short8 a = *(const short8*)&qbase[(size_t)(m * 16 + fr) * INNER + kk * 32 + g * 8];
            int krow = n * 16 + fr;
            short8 kf = *(const short8*)((const char*)Ks + krow * 128 + ((((kk << 2) + g) ^ (krow & 7)) << 4));
            acc = __builtin_amdgcn_mfma_f32_16x16x32_bf16(a, kf, acc, 0, 0, 0);
        }
        int i0 = m * 16 + g * 4;
        int kap = n * 16 + fr;
        const float* bR = biasR + ((size_t)h * NTOK + i0) * 96 + kap;
        #pragma unroll
        for (int r = 0; r < 4; ++r)
            Sls[(i0 + r) * SROW + kap] = acc[r] * 0.125f + bR[r * 96];
    }
    __syncthreads();

    for (int rr = 0; rr < 20; ++rr) {
        int row = wid + 4 * rr;
        const float* Srow = Sls + row * SROW;
        float s0 = Srow[lane];
        float s1v = Srow[64 + (lane & 31)];
        float mx = fmaxf(s0, s1v);
        #pragma unroll
        for (int o = 32; o > 0; o >>= 1) mx = fmaxf(mx, __shfl_xor(mx, o));
        float e0 = __expf(s0 - mx);
        float e1 = (lane < 32) ? __expf(s1v - mx) : 0.0f;
        float sum = e0 + e1;
        #pragma unroll
        for (int o = 32; o > 0; o >>= 1) sum += __shfl_xor(sum, o);
        float inv = 1.0f / sum;
        *(unsigned short*)(Sb + row * (SROW * 4) + lane * 2) = f2bf(e0 * inv);
        if (lane < 32)
            *(unsigned short*)(Sb + row * (SROW * 4) + 128 + lane * 2) = f2bf(e1 * inv);
    }
    __syncthreads();

    for (int s = 0; s < 5; ++s) {
        int tt = wid + 4 * s;
        int m = tt >> 2, n = tt & 3;
        f32x4 acc = {};
        #pragma unroll
        for (int kc = 0; kc < 3; ++kc) {
            short8 p = *(const short8*)(Sb + (m * 16 + fr) * (SROW * 4) + kc * 64 + g * 16);
            int drow = n * 16 + fr;
            short8 vv = *(const short8*)((const char*)Vt + drow * 256 + ((((kc << 2) + g) ^ (drow & 7)) << 4));
            acc = __builtin_amdgcn_mfma_f32_16x16x32_bf16(p, vv, acc, 0, 0, 0);
        }
        int i0 = m * 16 + g * 4;
        int d = n * 16 + fr;
        #pragma unroll
        for (int r = 0; r < 4; ++r)
            attnb[((size_t)(b * NTOK) + i0 + r) * INNER + h * DH + d] = __float2bfloat16(acc[r]);
    }
}

// fused FF1: act[M,3072] = (xn @ W1a) * silu(xn @ W1g), bf16 out.
// 128x64 tile (64 a-cols + 64 gate-cols), dbuf, counted vmcnt.
// acc = 16 f32x4 = 64 AGPR -> 2 waves/SIMD. LDS 64KB -> 2 blocks/CU.
__global__ __launch_bounds__(256, 2) void gemm_ff1(const bf16* __restrict__ A,
                                                   const bf16* __restrict__ W1T,
                                                   bf16* __restrict__ act) {
    __shared__ __align__(16) short As[2 * 128 * 64];
    __shared__ __align__(16) short Bs1[2 * 64 * 64];
    __shared__ __align__(16) short Bs2[2 * 64 * 64];
    const int t = threadIdx.x;
    const int lane = t & 63;
    const int wid = t >> 6;
    const int wr = wid >> 1, wc = wid & 1;
    const int fr = lane & 15;
    const int kb = lane >> 4;
    const int row0 = blockIdx.y * 128, col0 = blockIdx.x * 64;
    const int K = DIM;
    const bf16* B1 = W1T;
    const bf16* B2 = W1T + (size_t)FFH * DIM;

    f32x4 acc1[4][2] = {}, acc2[4][2] = {};
    const int NKT = DIM >> 6;

    GSTAGE_N(4, As, A, row0, K, 0)
    GSTAGE_N(2, Bs1, B1, col0, K, 0)
    GSTAGE_N(2, Bs2, B2, col0, K, 0)

    for (int kt = 0; kt < NKT; ++kt) {
        const short* curA  = As  + (kt & 1) * (128 * 64);
        const short* curB1 = Bs1 + (kt & 1) * (64 * 64);
        const short* curB2 = Bs2 + (kt & 1) * (64 * 64);
        if (kt + 1 < NKT) {
            short* nxtA  = As  + ((kt + 1) & 1) * (128 * 64);
            short* nxtB1 = Bs1 + ((kt + 1) & 1) * (64 * 64);
            short* nxtB2 = Bs2 + ((kt + 1) & 1) * (64 * 64);
            int k0n = (kt + 1) << 6;
            GSTAGE_N(4, nxtA, A, row0, K, k0n)
            GSTAGE_N(2, nxtB1, B1, col0, K, k0n)
            GSTAGE_N(2, nxtB2, B2, col0, K, k0n)
            WAITV(8);       // current tile's 8 loads done; next 8 in flight
        } else {
            WAITV(0);
        }
        BARRIER();
        #pragma unroll
        for (int kk = 0; kk < 2; ++kk) {
            short8 af[4], b1v[2], b2v[2];
            FRAG_READ(af, curA, wr * 64, kk)
            FRAG_READ2(b1v, curB1, wc * 32, kk)
            FRAG_READ2(b2v, curB2, wc * 32, kk)
            __builtin_amdgcn_s_setprio(1);
            #pragma unroll
            for (int i = 0; i < 4; ++i)
                #pragma unroll
                for (int j = 0; j < 2; ++j) {
                    acc1[i][j] = __builtin_amdgcn_mfma_f32_16x16x32_bf16(af[i], b1v[j], acc1[i][j], 0, 0, 0);
                    acc2[i][j] = __builtin_amdgcn_mfma_f32_16x16x32_bf16(af[i], b2v[j], acc2[i][j], 0, 0, 0);
                }
            __builtin_amdgcn_s_setprio(0);
        }
        BARRIER();
    }

    #pragma unroll
    for (int i = 0; i < 4; ++i) {
        #pragma unroll
        for (int j = 0; j < 2; ++j) {
            int row = row0 + wr * 64 + i * 16 + kb * 4;
            int col = col0 + wc * 32 + j * 16 + fr;
            #pragma unroll
            for (int r = 0; r < 4; ++r) {
                float a = acc1[i][j][r];
                float gt = acc2[i][j][r];
                float s = a * gt / (1.0f + __expf(-gt));
                act[(size_t)(row + r) * FFH + col] = __float2bfloat16(s);
            }
        }
    }
}

// ---------------- output extraction ----------------
__global__ void extract(const float* __restrict__ x, float* __restrict__ out) {
    int idx = blockIdx.x * 256 + threadIdx.x;
    if (idx >= NB * DIM) return;
    int b = idx / DIM, d = idx % DIM;
    out[idx] = x[((size_t)(b * NTOK + NTOK - 1)) * DIM + d];
}

extern "C" void kernel_launch(void* const* d_in, const int* in_sizes, int n_in,
                              void* d_out, int out_size, void* d_ws, size_t ws_size,
                              hipStream_t stream) {
    (void)in_sizes; (void)n_in; (void)out_size; (void)ws_size;
    const float* text_enc = (const float*)d_in[1];
    const float* text_emb = (const float*)d_in[2];
    const float* time_tab = (const float*)d_in[3];
    const float* lquery   = (const float*)d_in[4];
    const float* rel_tab  = (const float*)d_in[5];
    const float* attn_g   = (const float*)d_in[6];
    const float* Wq       = (const float*)d_in[7];
    const float* Wkv      = (const float*)d_in[8];
    const float* Wout     = (const float*)d_in[9];
    const float* null_kv  = (const float*)d_in[10];
    const float* ff_g     = (const float*)d_in[11];
    const float* Wff1     = (const float*)d_in[12];
    const float* Wff2     = (const float*)d_in[13];
    const int*   tsteps   = (const int*)d_in[14];

    // ---- workspace layout (bytes, all 16-aligned) ----
    char* ws = (char*)d_ws;
    float* x     = (float*)(ws);                        // 62,914,560
    bf16*  xn    = (bf16*)(ws + 62914560);              // 31,457,280 (attn out aliases)
    bf16*  attnb = xn;
    char*  U     = ws + 94371840;                       // union region: 125,829,120
    bf16*  qb    = (bf16*)U;                            //  31,457,280
    bf16*  kbuf  = (bf16*)(U + 31457280);               //   2,621,440
    bf16*  vT    = (bf16*)(U + 34078720);               //   2,621,440
    bf16*  act   = (bf16*)U;                            // 125,829,120 (FF phase)
    float* biasR = (float*)(ws + 220200960);            //     368,640
    bf16*  WqT   = (bf16*)(ws + 220569600);             //   1,179,648
    bf16*  WkvT  = (bf16*)(ws + 221749248);             //     196,608
    bf16*  WoutT = (bf16*)(ws + 221945856);             //   1,179,648
    bf16*  Wff1T = (bf16*)(ws + 223125504);             //   9,437,184
    bf16*  Wff2T = (bf16*)(ws + 232562688);             //   4,718,592  -> end 237,281,280

    build_tokens<<<(NROWS * DIM + 255) / 256, 256, 0, stream>>>(text_enc, text_emb, time_tab, lquery, tsteps, x);
    build_biasR<<<(HEADS * NTOK * 96 + 255) / 256, 256, 0, stream>>>(rel_tab, biasR);

    for (int l = 0; l < DEPTH; l++) {
        convT<<<dim3(INNER / 32, DIM / 32), 256, 0, stream>>>(Wq   + (size_t)l * DIM * INNER,  WqT,   DIM,   INNER);
        convT<<<dim3((2 * DH) / 32, DIM / 32), 256, 0, stream>>>(Wkv + (size_t)l * DIM * 2 * DH, WkvT, DIM, 2 * DH);
        convT<<<dim3(DIM / 32, INNER / 32), 256, 0, stream>>>(Wout + (size_t)l * INNER * DIM,  WoutT, INNER, DIM);
        convT<<<dim3(FF2C / 32, DIM / 32), 256, 0, stream>>>(Wff1 + (size_t)l * DIM * FF2C,    Wff1T, DIM,   FF2C);
        convT<<<dim3(DIM / 32, FFH / 32), 256, 0, stream>>>(Wff2  + (size_t)l * FFH * DIM,     Wff2T, FFH,   DIM);

        // ---- attention block ----
        rmsnorm_w<<<NROWS / (8 * 4), 256, 0, stream>>>(x, attn_g + (size_t)l * DIM, xn);
        gemm_bt<2><<<dim3(INNER / 128, NROWS / 128), 256, 0, stream>>>(xn, WqT, (float*)qb, INNER, DIM);
        gemm_kv<<<dim3(1, NROWS / 128), 256, 0, stream>>>(xn, WkvT, kbuf, vT);
        attn_mfma<<<NB * HEADS, 256, 0, stream>>>(qb, kbuf, vT, null_kv + (size_t)l * 2 * DH, biasR, attnb);
        gemm_bt<1><<<dim3(DIM / 128, NROWS / 128), 256, 0, stream>>>(attnb, WoutT, x, DIM, INNER);

        // ---- feedforward block ----
        rmsnorm_w<<<NROWS / (8 * 4), 256, 0, stream>>>(x, ff_g + (size_t)l * DIM, xn);
        gemm_ff1<<<dim3(FFH / 64, NROWS / 128), 256, 0, stream>>>(xn, Wff1T, act);
        gemm_bt<1><<<dim3(DIM / 128, NROWS / 128), 256, 0, stream>>>(act, Wff2T, x, DIM, FFH);
    }

    extract<<<(NB * DIM + 255) / 256, 256, 0, stream>>>(x, (float*)d_out);
}